// Round 1
// baseline (58.433 us; speedup 1.0000x reference)
//
#include <hip/hip_runtime.h>

// Projection (cone-beam DRR style): D=W=H=128 volume, 180x180 detector, BATCH=4.
// out[b][0][i][j] = dx(b,i,j) * sum_{k=0..127} trilinear(vol, ray(b,i,j,k))
//
// Index-space ray is linear in k:
//   grid_x(k) = ex + Ix*(k-ey)/Iy   (Iy = -ey)
//   grid_y(k) = k                    (exactly, by construction)
//   grid_z(k) = ez + Iz*(k-ey)/Iy
// Volume indices (align_corners=True, 128-wide dims):
//   iz = 63.5 + grid_x * (63.5/64)   (D axis, stride 2^14)
//   iy = k * (63.5/64)               (W axis, stride 2^7)
//   ix = 63.5 + grid_z * (63.5/64)   (H axis, stride 1)

#define RES 180
#define NPIX (4 * RES * RES)   // 129600
#define PIX_PER_BLOCK 64
#define KSPLIT 4

__global__ __launch_bounds__(256) void proj_kernel(
    const float* __restrict__ vol, const float* __restrict__ poses,
    const float* __restrict__ spacing, float* __restrict__ out) {
  const int tid = threadIdx.x;
  const int lp  = tid & 63;       // pixel slot in block
  const int ks  = tid >> 6;       // k-chunk 0..3
  const int gpix = blockIdx.x * PIX_PER_BLOCK + lp;

  const int b   = gpix / (RES * RES);
  const int rem = gpix - b * (RES * RES);
  const int i   = rem / RES;
  const int j   = rem - i * RES;

  const float ex = poses[b * 3 + 0];
  const float ey = poses[b * 3 + 1];
  const float ez = poses[b * 3 + 2];

  const float gx = (float)i - 90.0f;   // lin_x[i]
  const float gy = (float)j - 90.0f;   // lin_y[j]
  const float Ix = gx - ex;
  const float Iy = -ey;                // ~ +300
  const float Iz = gy - ez;

  const float c     = 63.5f / 64.0f;   // 0.9921875 exact in fp32
  const float invIy = 1.0f / Iy;

  // iz(k) = 63.5 + (ex + Ix*(1 + k/Iy)) * c  ->  base + k*step
  const float izb = fmaf(ex + Ix, c, 63.5f);
  const float izs = Ix * invIy * c;
  const float ixb = fmaf(ez + Iz, c, 63.5f);
  const float ixs = Iz * invIy * c;

  float sum = 0.0f;
  const int k0 = ks * 32;
#pragma unroll 4
  for (int k = k0; k < k0 + 32; ++k) {
    const float kf = (float)k;
    const float ix = fmaf(kf, ixs, ixb);
    const float iy = kf * c;
    const float iz = fmaf(kf, izs, izb);

    const float fx = floorf(ix), fy = floorf(iy), fz = floorf(iz);
    const int x0 = (int)fx, y0 = (int)fy, z0 = (int)fz;

    const float wx1 = ix - fx, wy1 = iy - fy, wz1 = iz - fz;
    const float wx0 = 1.0f - wx1, wy0 = 1.0f - wy1, wz0 = 1.0f - wz1;

    // per-axis masked weights == reference's per-corner zero padding
    const float vx0 = ((unsigned)x0       < 128u) ? wx0 : 0.0f;
    const float vx1 = ((unsigned)(x0 + 1) < 128u) ? wx1 : 0.0f;
    const float vy0 = ((unsigned)y0       < 128u) ? wy0 : 0.0f;
    const float vy1 = ((unsigned)(y0 + 1) < 128u) ? wy1 : 0.0f;
    const float vz0 = ((unsigned)z0       < 128u) ? wz0 : 0.0f;
    const float vz1 = ((unsigned)(z0 + 1) < 128u) ? wz1 : 0.0f;

    const int xc0 = min(max(x0, 0), 127), xc1 = min(max(x0 + 1, 0), 127);
    const int yc0 = min(max(y0, 0), 127), yc1 = min(max(y0 + 1, 0), 127);
    const int zc0 = min(max(z0, 0), 127), zc1 = min(max(z0 + 1, 0), 127);

    const float* p00 = vol + ((zc0 << 14) + (yc0 << 7));
    const float* p01 = vol + ((zc0 << 14) + (yc1 << 7));
    const float* p10 = vol + ((zc1 << 14) + (yc0 << 7));
    const float* p11 = vol + ((zc1 << 14) + (yc1 << 7));

    const float v000 = p00[xc0], v001 = p00[xc1];
    const float v010 = p01[xc0], v011 = p01[xc1];
    const float v100 = p10[xc0], v101 = p10[xc1];
    const float v110 = p11[xc0], v111 = p11[xc1];

    const float s00 = fmaf(vx1, v001, vx0 * v000);
    const float s01 = fmaf(vx1, v011, vx0 * v010);
    const float s10 = fmaf(vx1, v101, vx0 * v100);
    const float s11 = fmaf(vx1, v111, vx0 * v110);
    const float s0  = fmaf(vy1, s01, vy0 * s00);
    const float s1  = fmaf(vy1, s11, vy0 * s10);

    sum = fmaf(vz0, s0, sum);
    sum = fmaf(vz1, s1, sum);
  }

  __shared__ float part[256];
  part[tid] = sum;
  __syncthreads();

  if (tid < 64) {
    const float tot = part[tid] + part[tid + 64] + part[tid + 128] + part[tid + 192];
    const float sxp = spacing[0], syp = spacing[1], szp = spacing[2];
    const float ax = Ix * invIy * sxp;
    const float az = Iz * invIy * szp;
    const float dxl = sqrtf(fmaf(ax, ax, fmaf(az, az, syp * syp)));
    out[gpix] = tot * dxl;
  }
}

extern "C" void kernel_launch(void* const* d_in, const int* in_sizes, int n_in,
                              void* d_out, int out_size, void* d_ws, size_t ws_size,
                              hipStream_t stream) {
  const float* vol     = (const float*)d_in[0];   // I_rec [1,1,128,128,128] fp32
  const float* poses   = (const float*)d_in[1];   // [4,3] fp32
  const float* spacing = (const float*)d_in[2];   // [3] fp32
  float* out = (float*)d_out;                     // [4,1,180,180] fp32

  proj_kernel<<<NPIX / PIX_PER_BLOCK, 256, 0, stream>>>(vol, poses, spacing, out);
}

// Round 2
// 55.309 us; speedup vs baseline: 1.0565x; 1.0565x over previous
//
#include <hip/hip_runtime.h>

// Projection (cone-beam DRR): D=W=H=128 volume, 180x180 detector, BATCH=4.
// out[b][0][i][j] = dx(b,i,j) * sum_{k=0..127} trilinear(vol, ray(b,i,j,k))
//
// Index-space ray is linear in k:
//   iz(k) = izb + k*izs   (D axis, stride 2^14)  -- depends on row i only
//   iy(k) = k * c         (W axis, stride 2^7)   -- ALWAYS in [0,126.01] -> no y mask
//   ix(k) = ixb + k*ixs   (H axis, stride 1)     -- depends on col j only
// A sample contributes iff ix in (-1,128) AND iz in (-1,128); both are linear
// in k, so each thread loops only its exact valid k-subinterval. ~49% of
// pixels (outside the projected volume footprint) skip the loop entirely.

#define RES 180
#define NPIX (4 * RES * RES)   // 129600
#define PIX_PER_BLOCK 64

__global__ __launch_bounds__(256) void proj_kernel(
    const float* __restrict__ vol, const float* __restrict__ poses,
    const float* __restrict__ spacing, float* __restrict__ out) {
  const int tid = threadIdx.x;
  const int lp  = tid & 63;       // pixel slot in block
  const int ks  = tid >> 6;       // k-chunk 0..3
  const int gpix = blockIdx.x * PIX_PER_BLOCK + lp;

  const int b   = gpix / (RES * RES);
  const int rem = gpix - b * (RES * RES);
  const int i   = rem / RES;
  const int j   = rem - i * RES;

  const float ex = poses[b * 3 + 0];
  const float ey = poses[b * 3 + 1];
  const float ez = poses[b * 3 + 2];

  const float gx = (float)i - 90.0f;   // lin_x[i]
  const float gy = (float)j - 90.0f;   // lin_y[j]
  const float Ix = gx - ex;
  const float Iy = -ey;                // ~ +300
  const float Iz = gy - ez;

  const float c     = 63.5f / 64.0f;   // 0.9921875 exact in fp32
  const float invIy = 1.0f / Iy;

  const float izb = fmaf(ex + Ix, c, 63.5f);
  const float izs = Ix * invIy * c;
  const float ixb = fmaf(ez + Iz, c, 63.5f);
  const float ixs = Iz * invIy * c;

  // ---- per-thread valid k-interval: ix,iz in (-1,128), k in [k0, k0+32) ----
  const int k0 = ks * 32;
  float ka = (float)k0;
  float kb = (float)(k0 + 32);
  {
    // x axis
    if (ixs > 1e-12f)       { ka = fmaxf(ka, (-1.0f - ixb) / ixs); kb = fminf(kb, (128.0f - ixb) / ixs); }
    else if (ixs < -1e-12f) { ka = fmaxf(ka, (128.0f - ixb) / ixs); kb = fminf(kb, (-1.0f - ixb) / ixs); }
    else if (ixb <= -1.0f || ixb >= 128.0f) { kb = ka; }
    // z axis
    if (izs > 1e-12f)       { ka = fmaxf(ka, (-1.0f - izb) / izs); kb = fminf(kb, (128.0f - izb) / izs); }
    else if (izs < -1e-12f) { ka = fmaxf(ka, (128.0f - izb) / izs); kb = fminf(kb, (-1.0f - izb) / izs); }
    else if (izb <= -1.0f || izb >= 128.0f) { kb = ka; }
    ka = fmaxf(ka, (float)k0);
    kb = fminf(kb, (float)(k0 + 32));
  }
  const int kai = (int)ceilf(ka);
  const int kbi = (int)ceilf(kb);   // loop k in [kai, kbi); masks make edges exact

  float sum = 0.0f;
#pragma unroll 2
  for (int k = kai; k < kbi; ++k) {
    const float kf = (float)k;
    const float ix = fmaf(kf, ixs, ixb);
    const float iy = kf * c;                 // in [0, 126.01]: y never out of bounds
    const float iz = fmaf(kf, izs, izb);

    const float fx = floorf(ix), fy = floorf(iy), fz = floorf(iz);
    const int x0 = (int)fx, y0 = (int)fy, z0 = (int)fz;

    const float wx1 = ix - fx, wy1 = iy - fy, wz1 = iz - fz;
    const float wx0 = 1.0f - wx1, wy0 = 1.0f - wy1, wz0 = 1.0f - wz1;

    // x/z per-axis masked weights == reference's per-corner zero padding
    const float vx0 = ((unsigned)x0       < 128u) ? wx0 : 0.0f;
    const float vx1 = ((unsigned)(x0 + 1) < 128u) ? wx1 : 0.0f;
    const float vz0 = ((unsigned)z0       < 128u) ? wz0 : 0.0f;
    const float vz1 = ((unsigned)(z0 + 1) < 128u) ? wz1 : 0.0f;

    const int xc0 = min(max(x0, 0), 127), xc1 = min(max(x0 + 1, 0), 127);
    const int zc0 = min(max(z0, 0), 127), zc1 = min(max(z0 + 1, 0), 127);

    const float* p00 = vol + ((zc0 << 14) + (y0 << 7));
    const float* p01 = p00 + 128;            // y0+1 (always valid)
    const float* p10 = vol + ((zc1 << 14) + (y0 << 7));
    const float* p11 = p10 + 128;

    const float v000 = p00[xc0], v001 = p00[xc1];
    const float v010 = p01[xc0], v011 = p01[xc1];
    const float v100 = p10[xc0], v101 = p10[xc1];
    const float v110 = p11[xc0], v111 = p11[xc1];

    const float s00 = fmaf(vx1, v001, vx0 * v000);
    const float s01 = fmaf(vx1, v011, vx0 * v010);
    const float s10 = fmaf(vx1, v101, vx0 * v100);
    const float s11 = fmaf(vx1, v111, vx0 * v110);
    const float s0  = fmaf(wy1, s01, wy0 * s00);
    const float s1  = fmaf(wy1, s11, wy0 * s10);

    sum = fmaf(vz0, s0, sum);
    sum = fmaf(vz1, s1, sum);
  }

  __shared__ float part[256];
  part[tid] = sum;
  __syncthreads();

  if (tid < 64) {
    const float tot = part[tid] + part[tid + 64] + part[tid + 128] + part[tid + 192];
    const float sxp = spacing[0], syp = spacing[1], szp = spacing[2];
    const float ax = Ix * invIy * sxp;
    const float az = Iz * invIy * szp;
    const float dxl = sqrtf(fmaf(ax, ax, fmaf(az, az, syp * syp)));
    out[gpix] = tot * dxl;
  }
}

extern "C" void kernel_launch(void* const* d_in, const int* in_sizes, int n_in,
                              void* d_out, int out_size, void* d_ws, size_t ws_size,
                              hipStream_t stream) {
  const float* vol     = (const float*)d_in[0];   // I_rec [1,1,128,128,128] fp32
  const float* poses   = (const float*)d_in[1];   // [4,3] fp32
  const float* spacing = (const float*)d_in[2];   // [3] fp32
  float* out = (float*)d_out;                     // [4,1,180,180] fp32

  proj_kernel<<<NPIX / PIX_PER_BLOCK, 256, 0, stream>>>(vol, poses, spacing, out);
}

// Round 3
// 30.463 us; speedup vs baseline: 1.9181x; 1.8156x over previous
//
#include <hip/hip_runtime.h>

// Cone-beam projection: D=W=H=128 volume, 180x180 detector, BATCH=4.
// out[b][0][i][j] = dx(b,i,j) * sum_{k=0..127} trilinear(vol, ray(b,i,j,k))
//
// Ray is linear in k in index space:
//   iz(k) = izb + k*izs  (D axis, stride 2^14)   iy(k) = k*c in [0,126.01] (W axis, never OOB)
//   ix(k) = ixb + k*ixs  (H axis, stride 1)
// Each thread loops only its valid k-subinterval (ix,iz in (-1,128)).
// Block->pixel-chunk mapping is swizzled by a coprime stride so heavy
// (central) chunks spread evenly across CUs: the whole 2025-block grid is
// device-resident at once, so spatial clustering = per-CU imbalance.
// x-neighbor pair loaded as one unaligned float2 (dword-aligned is legal).

#define RES 180
#define NPIX (4 * RES * RES)    // 129600
#define NCHUNK (NPIX / 64)      // 2025
#define CHUNK_STRIDE 1013       // coprime to 2025 = 3^4 * 5^2

typedef struct __attribute__((packed, aligned(4))) { float x, y; } f2u;

__global__ __launch_bounds__(256) void proj_kernel(
    const float* __restrict__ vol, const float* __restrict__ poses,
    const float* __restrict__ spacing, float* __restrict__ out) {
  const int tid = threadIdx.x;
  const int lp  = tid & 63;       // pixel slot in chunk
  const int ks  = tid >> 6;       // k-chunk 0..3
  const int chunk = (int)(((long long)blockIdx.x * CHUNK_STRIDE) % NCHUNK);
  const int gpix = chunk * 64 + lp;

  const int b   = gpix / (RES * RES);
  const int rem = gpix - b * (RES * RES);
  const int i   = rem / RES;
  const int j   = rem - i * RES;

  const float ex = poses[b * 3 + 0];
  const float ey = poses[b * 3 + 1];
  const float ez = poses[b * 3 + 2];

  const float gx = (float)i - 90.0f;   // lin_x[i]
  const float gy = (float)j - 90.0f;   // lin_y[j]
  const float Ix = gx - ex;
  const float Iy = -ey;                // ~ +300
  const float Iz = gy - ez;

  const float c     = 63.5f / 64.0f;   // 0.9921875 exact in fp32
  const float invIy = 1.0f / Iy;

  const float izb = fmaf(ex + Ix, c, 63.5f);
  const float izs = Ix * invIy * c;
  const float ixb = fmaf(ez + Iz, c, 63.5f);
  const float ixs = Iz * invIy * c;

  // ---- per-thread valid k-interval: ix,iz in (-1,128), k in [k0, k0+32) ----
  const int k0 = ks * 32;
  float ka = (float)k0;
  float kb = (float)(k0 + 32);
  {
    if (ixs > 1e-12f)       { ka = fmaxf(ka, (-1.0f - ixb) / ixs); kb = fminf(kb, (128.0f - ixb) / ixs); }
    else if (ixs < -1e-12f) { ka = fmaxf(ka, (128.0f - ixb) / ixs); kb = fminf(kb, (-1.0f - ixb) / ixs); }
    else if (ixb <= -1.0f || ixb >= 128.0f) { kb = ka; }
    if (izs > 1e-12f)       { ka = fmaxf(ka, (-1.0f - izb) / izs); kb = fminf(kb, (128.0f - izb) / izs); }
    else if (izs < -1e-12f) { ka = fmaxf(ka, (128.0f - izb) / izs); kb = fminf(kb, (-1.0f - izb) / izs); }
    else if (izb <= -1.0f || izb >= 128.0f) { kb = ka; }
    ka = fmaxf(ka, (float)k0);
    kb = fminf(kb, (float)(k0 + 32));
  }
  const int kai = (int)ceilf(ka);
  const int kbi = (int)ceilf(kb);   // loop k in [kai, kbi); masks keep edges exact

  float sum = 0.0f;
#pragma unroll 2
  for (int k = kai; k < kbi; ++k) {
    const float kf = (float)k;
    const float ix = fmaf(kf, ixs, ixb);
    const float iy = kf * c;                 // y never out of bounds
    const float iz = fmaf(kf, izs, izb);

    const float fx = floorf(ix), fy = floorf(iy), fz = floorf(iz);
    const int x0 = (int)fx, y0 = (int)fy, z0 = (int)fz;

    const float wx1 = ix - fx, wy1 = iy - fy, wz1 = iz - fz;
    const float wx0 = 1.0f - wx1, wy0 = 1.0f - wy1, wz0 = 1.0f - wz1;

    // x/z per-axis masked weights == reference's zero padding
    const float vx0 = ((unsigned)x0       < 128u) ? wx0 : 0.0f;
    const float vx1 = ((unsigned)(x0 + 1) < 128u) ? wx1 : 0.0f;
    const float vz0 = ((unsigned)z0       < 128u) ? wz0 : 0.0f;
    const float vz1 = ((unsigned)(z0 + 1) < 128u) ? wz1 : 0.0f;

    // one float2 covers both x-neighbors; at edges swap the weights instead
    const int xb2 = min(max(x0, 0), 126);
    const bool in = (x0 == xb2);
    const float wlo = in ? vx0 : vx1;
    const float whi = in ? vx1 : vx0;

    const int zc0 = min(max(z0, 0), 127), zc1 = min(max(z0 + 1, 0), 127);
    const float* base = vol + ((zc0 << 14) + (y0 << 7) + xb2);
    const int dz = (zc1 - zc0) << 14;

    const f2u v00 = *(const f2u*)(base);
    const f2u v01 = *(const f2u*)(base + 128);
    const f2u v10 = *(const f2u*)(base + dz);
    const f2u v11 = *(const f2u*)(base + dz + 128);

    const float s00 = fmaf(whi, v00.y, wlo * v00.x);
    const float s01 = fmaf(whi, v01.y, wlo * v01.x);
    const float s10 = fmaf(whi, v10.y, wlo * v10.x);
    const float s11 = fmaf(whi, v11.y, wlo * v11.x);
    const float s0  = fmaf(wy1, s01, wy0 * s00);
    const float s1  = fmaf(wy1, s11, wy0 * s10);

    sum = fmaf(vz0, s0, sum);
    sum = fmaf(vz1, s1, sum);
  }

  __shared__ float part[256];
  part[tid] = sum;
  __syncthreads();

  if (tid < 64) {
    const float tot = part[tid] + part[tid + 64] + part[tid + 128] + part[tid + 192];
    const float sxp = spacing[0], syp = spacing[1], szp = spacing[2];
    const float ax = Ix * invIy * sxp;
    const float az = Iz * invIy * szp;
    const float dxl = sqrtf(fmaf(ax, ax, fmaf(az, az, syp * syp)));
    out[gpix] = tot * dxl;
  }
}

extern "C" void kernel_launch(void* const* d_in, const int* in_sizes, int n_in,
                              void* d_out, int out_size, void* d_ws, size_t ws_size,
                              hipStream_t stream) {
  const float* vol     = (const float*)d_in[0];   // I_rec [1,1,128,128,128] fp32
  const float* poses   = (const float*)d_in[1];   // [4,3] fp32
  const float* spacing = (const float*)d_in[2];   // [3] fp32
  float* out = (float*)d_out;                     // [4,1,180,180] fp32

  proj_kernel<<<NCHUNK, 256, 0, stream>>>(vol, poses, spacing, out);
}

// Round 4
// 26.987 us; speedup vs baseline: 2.1652x; 1.1288x over previous
//
#include <hip/hip_runtime.h>

// Cone-beam projection: D=W=H=128 volume, 180x180 detector, BATCH=4.
// out[b][0][i][j] = dx(b,i,j) * sum_{k=0..127} trilinear(vol, ray(b,i,j,k))
//
// Ray is linear in k in index space:
//   iz(k) = izb + k*izs  (D axis, stride 2^14)
//   iy(k) = k*c in [0,126.01] (W axis, never OOB)
//   ix(k) = ixb + k*ixs  (H axis, stride 1)
// Each thread loops only its valid k-subinterval (ix,iz in (-1,128)).
//
// KSPLIT=8 (16 k per thread, 32 pixels/block): grid = 4050 blocks = 2x device
// residency, so dead (out-of-footprint) blocks that exit early get REPLACED
// from the dispatch queue, and live-wave TLP approaches the 8-waves/SIMD cap
// (this kernel is L2-gather-latency bound; TLP is the hiding mechanism).
// Coprime chunk swizzle spreads heavy central chunks across CUs.

#define RES 180
#define NPIX (4 * RES * RES)    // 129600
#define PIX_PER_BLOCK 32
#define NCHUNK (NPIX / PIX_PER_BLOCK)   // 4050 = 2*3^4*5^2
#define CHUNK_STRIDE 1013               // prime, coprime to 4050

typedef struct __attribute__((packed, aligned(4))) { float x, y; } f2u;

__global__ __launch_bounds__(256) void proj_kernel(
    const float* __restrict__ vol, const float* __restrict__ poses,
    const float* __restrict__ spacing, float* __restrict__ out) {
  const int tid = threadIdx.x;
  const int lp  = tid & 31;       // pixel slot in chunk
  const int ks  = tid >> 5;       // k-chunk 0..7 (16 k each)
  const int chunk = (int)(((long long)blockIdx.x * CHUNK_STRIDE) % NCHUNK);
  const int gpix = chunk * PIX_PER_BLOCK + lp;

  const int b   = gpix / (RES * RES);
  const int rem = gpix - b * (RES * RES);
  const int i   = rem / RES;
  const int j   = rem - i * RES;

  const float ex = poses[b * 3 + 0];
  const float ey = poses[b * 3 + 1];
  const float ez = poses[b * 3 + 2];

  const float gx = (float)i - 90.0f;   // lin_x[i]
  const float gy = (float)j - 90.0f;   // lin_y[j]
  const float Ix = gx - ex;
  const float Iy = -ey;                // ~ +300
  const float Iz = gy - ez;

  const float c     = 63.5f / 64.0f;   // 0.9921875 exact in fp32
  const float invIy = 1.0f / Iy;

  const float izb = fmaf(ex + Ix, c, 63.5f);
  const float izs = Ix * invIy * c;
  const float ixb = fmaf(ez + Iz, c, 63.5f);
  const float ixs = Iz * invIy * c;

  // ---- per-thread valid k-interval: ix,iz in (-1,128), k in [k0, k0+16) ----
  const int k0 = ks * 16;
  float ka = (float)k0;
  float kb = (float)(k0 + 16);
  {
    if (ixs > 1e-12f)       { ka = fmaxf(ka, (-1.0f - ixb) / ixs); kb = fminf(kb, (128.0f - ixb) / ixs); }
    else if (ixs < -1e-12f) { ka = fmaxf(ka, (128.0f - ixb) / ixs); kb = fminf(kb, (-1.0f - ixb) / ixs); }
    else if (ixb <= -1.0f || ixb >= 128.0f) { kb = ka; }
    if (izs > 1e-12f)       { ka = fmaxf(ka, (-1.0f - izb) / izs); kb = fminf(kb, (128.0f - izb) / izs); }
    else if (izs < -1e-12f) { ka = fmaxf(ka, (128.0f - izb) / izs); kb = fminf(kb, (-1.0f - izb) / izs); }
    else if (izb <= -1.0f || izb >= 128.0f) { kb = ka; }
    ka = fmaxf(ka, (float)k0);
    kb = fminf(kb, (float)(k0 + 16));
  }
  const int kai = (int)ceilf(ka);
  const int kbi = (int)ceilf(kb);   // loop k in [kai, kbi); masks keep edges exact

  float sum = 0.0f;
#pragma unroll 2
  for (int k = kai; k < kbi; ++k) {
    const float kf = (float)k;
    const float ix = fmaf(kf, ixs, ixb);
    const float iy = kf * c;                 // y never out of bounds
    const float iz = fmaf(kf, izs, izb);

    const float fx = floorf(ix), fy = floorf(iy), fz = floorf(iz);
    const int x0 = (int)fx, y0 = (int)fy, z0 = (int)fz;

    const float wx1 = ix - fx, wy1 = iy - fy, wz1 = iz - fz;
    const float wx0 = 1.0f - wx1, wy0 = 1.0f - wy1, wz0 = 1.0f - wz1;

    // x/z per-axis masked weights == reference's zero padding
    const float vx0 = ((unsigned)x0       < 128u) ? wx0 : 0.0f;
    const float vx1 = ((unsigned)(x0 + 1) < 128u) ? wx1 : 0.0f;
    const float vz0 = ((unsigned)z0       < 128u) ? wz0 : 0.0f;
    const float vz1 = ((unsigned)(z0 + 1) < 128u) ? wz1 : 0.0f;

    // one float2 covers both x-neighbors; at edges swap the weights instead
    const int xb2 = min(max(x0, 0), 126);
    const bool in = (x0 == xb2);
    const float wlo = in ? vx0 : vx1;
    const float whi = in ? vx1 : vx0;

    const int zc0 = min(max(z0, 0), 127), zc1 = min(max(z0 + 1, 0), 127);
    const float* base = vol + ((zc0 << 14) + (y0 << 7) + xb2);
    const int dz = (zc1 - zc0) << 14;

    const f2u v00 = *(const f2u*)(base);
    const f2u v01 = *(const f2u*)(base + 128);
    const f2u v10 = *(const f2u*)(base + dz);
    const f2u v11 = *(const f2u*)(base + dz + 128);

    const float s00 = fmaf(whi, v00.y, wlo * v00.x);
    const float s01 = fmaf(whi, v01.y, wlo * v01.x);
    const float s10 = fmaf(whi, v10.y, wlo * v10.x);
    const float s11 = fmaf(whi, v11.y, wlo * v11.x);
    const float s0  = fmaf(wy1, s01, wy0 * s00);
    const float s1  = fmaf(wy1, s11, wy0 * s10);

    sum = fmaf(vz0, s0, sum);
    sum = fmaf(vz1, s1, sum);
  }

  __shared__ float part[256];
  part[tid] = sum;
  __syncthreads();

  if (tid < PIX_PER_BLOCK) {
    float tot = 0.0f;
#pragma unroll
    for (int s = 0; s < 8; ++s) tot += part[tid + 32 * s];  // lanes hit distinct banks
    const float sxp = spacing[0], syp = spacing[1], szp = spacing[2];
    const float ax = Ix * invIy * sxp;
    const float az = Iz * invIy * szp;
    const float dxl = sqrtf(fmaf(ax, ax, fmaf(az, az, syp * syp)));
    out[gpix] = tot * dxl;
  }
}

extern "C" void kernel_launch(void* const* d_in, const int* in_sizes, int n_in,
                              void* d_out, int out_size, void* d_ws, size_t ws_size,
                              hipStream_t stream) {
  const float* vol     = (const float*)d_in[0];   // I_rec [1,1,128,128,128] fp32
  const float* poses   = (const float*)d_in[1];   // [4,3] fp32
  const float* spacing = (const float*)d_in[2];   // [3] fp32
  float* out = (float*)d_out;                     // [4,1,180,180] fp32

  proj_kernel<<<NCHUNK, 256, 0, stream>>>(vol, poses, spacing, out);
}